// Round 2
// baseline (2328.248 us; speedup 1.0000x reference)
//
#include <hip/hip_runtime.h>
#include <hip/hip_bf16.h>
#include <math.h>

// Problem constants
#define MB_ 4096   // B*L rows
#define DD_ 2048   // D
#define EE_ 4096   // E
#define LL_ 2048   // L
#define NN_ 16     // state dim
#define RR_ 128    // low-rank

using short8  = __attribute__((ext_vector_type(8))) short;
using floatx4 = __attribute__((ext_vector_type(4))) float;
typedef unsigned short ushort_t;

__device__ __forceinline__ float bf2f(ushort_t u) {
    unsigned int x = ((unsigned int)u) << 16;
    return __builtin_bit_cast(float, x);
}
__device__ __forceinline__ ushort_t f2bf(float f) {
    unsigned int x = __builtin_bit_cast(unsigned int, f);
    unsigned int lsb = (x >> 16) & 1u;
    x += 0x7fffu + lsb;
    return (ushort_t)(x >> 16);
}

// ---------------- weight conversion f32 -> bf16 ----------------
__global__ __launch_bounds__(256) void cvt_bf16_k(const float* __restrict__ src,
                                                  ushort_t* __restrict__ dst, int n4) {
    int i = blockIdx.x * 256 + threadIdx.x;
    if (i >= n4) return;
    float4 v = ((const float4*)src)[i];
    ushort_t* d = dst + (size_t)i * 4;
    d[0] = f2bf(v.x); d[1] = f2bf(v.y); d[2] = f2bf(v.z); d[3] = f2bf(v.w);
}

// pack W_Bm(16) + W_Cm(16) + W_d1(128) + zero-pad to [256][4096] bf16
__global__ __launch_bounds__(256) void pack_bcd1_k(const float* __restrict__ Wb,
                                                   const float* __restrict__ Wc,
                                                   const float* __restrict__ Wd1,
                                                   ushort_t* __restrict__ dst) {
    int i = blockIdx.x * 256 + threadIdx.x;      // i indexes groups of 4 elems
    int row = i >> 10;                            // (i*4)/4096
    int c4  = i & 1023;
    float4 v;
    if (row < 16)       v = ((const float4*)(Wb  + (size_t)row       * 4096))[c4];
    else if (row < 32)  v = ((const float4*)(Wc  + (size_t)(row - 16)* 4096))[c4];
    else if (row < 160) v = ((const float4*)(Wd1 + (size_t)(row - 32)* 4096))[c4];
    else { v.x = 0.f; v.y = 0.f; v.z = 0.f; v.w = 0.f; }
    ushort_t* d = dst + (size_t)i * 4;
    d[0] = f2bf(v.x); d[1] = f2bf(v.y); d[2] = f2bf(v.z); d[3] = f2bf(v.w);
}

// ---------------- RMSNorm ----------------
__global__ __launch_bounds__(256) void rmsnorm_k(const float* __restrict__ resid,
                                                 const float* __restrict__ nw,
                                                 ushort_t* __restrict__ xn) {
    __shared__ float red[4];
    int row = blockIdx.x;
    int tid = threadIdx.x;
    const float* rp = resid + (size_t)row * DD_;
    float4 a = ((const float4*)rp)[tid];
    float4 b = ((const float4*)rp)[tid + 256];
    float ss = a.x*a.x + a.y*a.y + a.z*a.z + a.w*a.w
             + b.x*b.x + b.y*b.y + b.z*b.z + b.w*b.w;
    #pragma unroll
    for (int off = 32; off; off >>= 1) ss += __shfl_xor(ss, off);
    int wave = tid >> 6;
    if ((tid & 63) == 0) red[wave] = ss;
    __syncthreads();
    float total = red[0] + red[1] + red[2] + red[3];
    float scale = rsqrtf(total * (1.0f / (float)DD_) + 1e-5f);
    ushort_t* op = xn + (size_t)row * DD_;
    int i0 = tid * 4;
    op[i0+0] = f2bf(a.x * scale * nw[i0+0]);
    op[i0+1] = f2bf(a.y * scale * nw[i0+1]);
    op[i0+2] = f2bf(a.z * scale * nw[i0+2]);
    op[i0+3] = f2bf(a.w * scale * nw[i0+3]);
    int i1 = (tid + 256) * 4;
    op[i1+0] = f2bf(b.x * scale * nw[i1+0]);
    op[i1+1] = f2bf(b.y * scale * nw[i1+1]);
    op[i1+2] = f2bf(b.z * scale * nw[i1+2]);
    op[i1+3] = f2bf(b.w * scale * nw[i1+3]);
}

// ---------------- bf16 MFMA GEMM: C[m,n] = sum_k A[m,k]*Bw[n,k] ----------------
#define GMODE_BF16     0
#define GMODE_F32      1
#define GMODE_SOFTPLUS 2
#define GMODE_RESID    3

__global__ __launch_bounds__(256) void gemm_bt(
    const ushort_t* __restrict__ A, const ushort_t* __restrict__ Bw,
    int lda, int ldb, int K,
    void* __restrict__ outp, int ldc, int ncols,
    const float* __restrict__ aux, int mode)
{
    __shared__ __align__(16) ushort_t As[128 * 32];
    __shared__ __align__(16) ushort_t Bs[128 * 32];
    const int tid  = threadIdx.x;
    const int lane = tid & 63;
    const int wave = tid >> 6;
    const int quad = lane >> 4;
    const int l16  = lane & 15;
    const int mb   = (wave & 1) * 64;
    const int nb   = (wave >> 1) * 64;
    const int tileM = blockIdx.y * 128;
    const int tileN = blockIdx.x * 128;

    const int r0   = tid >> 2;          // 0..63
    const int koff = (tid & 3) * 8;     // 0,8,16,24
    const ushort_t* Ag = A  + (size_t)(tileM + r0) * lda + koff;
    const ushort_t* Bg = Bw + (size_t)(tileN + r0) * ldb + koff;
    const int ldsoff = r0 * 32 + koff;

    floatx4 acc[4][4];
    #pragma unroll
    for (int i = 0; i < 4; i++)
        #pragma unroll
        for (int j = 0; j < 4; j++)
            acc[i][j] = (floatx4){0.f, 0.f, 0.f, 0.f};

    for (int kb = 0; kb < K; kb += 32) {
        uint4 a0 = *(const uint4*)(Ag + kb);
        uint4 a1 = *(const uint4*)(Ag + (size_t)64 * lda + kb);
        uint4 b0 = *(const uint4*)(Bg + kb);
        uint4 b1 = *(const uint4*)(Bg + (size_t)64 * ldb + kb);
        __syncthreads();
        *(uint4*)(As + ldsoff)           = a0;
        *(uint4*)(As + ldsoff + 64 * 32) = a1;
        *(uint4*)(Bs + ldsoff)           = b0;
        *(uint4*)(Bs + ldsoff + 64 * 32) = b1;
        __syncthreads();
        short8 af[4], bfr[4];
        #pragma unroll
        for (int i = 0; i < 4; i++)
            af[i] = *(const short8*)(As + (mb + i * 16 + l16) * 32 + quad * 8);
        #pragma unroll
        for (int j = 0; j < 4; j++)
            bfr[j] = *(const short8*)(Bs + (nb + j * 16 + l16) * 32 + quad * 8);
        #pragma unroll
        for (int i = 0; i < 4; i++)
            #pragma unroll
            for (int j = 0; j < 4; j++)
                acc[i][j] = __builtin_amdgcn_mfma_f32_16x16x32_bf16(af[i], bfr[j], acc[i][j], 0, 0, 0);
    }

    #pragma unroll
    for (int i = 0; i < 4; i++) {
        #pragma unroll
        for (int j = 0; j < 4; j++) {
            int col = tileN + nb + j * 16 + l16;
            if (col >= ncols) continue;
            int rowb = tileM + mb + i * 16 + quad * 4;
            #pragma unroll
            for (int r = 0; r < 4; r++) {
                size_t idx = (size_t)(rowb + r) * ldc + col;
                float v = acc[i][j][r];
                if (mode == GMODE_BF16) {
                    ((ushort_t*)outp)[idx] = f2bf(v);
                } else if (mode == GMODE_F32) {
                    ((float*)outp)[idx] = v;
                } else if (mode == GMODE_SOFTPLUS) {
                    float z = v + aux[col];
                    float sp = (z > 20.f) ? z : log1pf(expf(z));
                    ((ushort_t*)outp)[idx] = f2bf(sp);
                } else { // GMODE_RESID
                    ((float*)outp)[idx] = v + aux[idx];
                }
            }
        }
    }
}

// ---------------- depthwise causal conv (K=4) + bias + silu (bf16 in/out) ----------------
__global__ __launch_bounds__(256) void conv_silu_k(const ushort_t* __restrict__ xin,
                                                   const float* __restrict__ cw,
                                                   const float* __restrict__ cb,
                                                   ushort_t* __restrict__ xs) {
    int e  = blockIdx.x * 256 + threadIdx.x;
    int l0 = blockIdx.y * 4;
    int b  = blockIdx.z;
    float w0 = cw[e * 4 + 0], w1 = cw[e * 4 + 1], w2 = cw[e * 4 + 2], w3 = cw[e * 4 + 3];
    float bias = cb[e];
    const ushort_t* p = xin + ((size_t)(b * LL_ + l0)) * EE_ + e;
    ushort_t*       o = xs  + ((size_t)(b * LL_ + l0)) * EE_ + e;
    float v[7];
    #pragma unroll
    for (int j = 0; j < 7; j++) {
        int l = l0 + j - 3;
        v[j] = (l >= 0) ? bf2f(p[(ptrdiff_t)(j - 3) * EE_]) : 0.f;  // l0+3 <= L-1 always
    }
    #pragma unroll
    for (int r = 0; r < 4; r++) {
        float s = bias + v[r] * w0 + v[r+1] * w1 + v[r+2] * w2 + v[r+3] * w3;
        float out = s / (1.f + expf(-s));           // silu
        o[(size_t)r * EE_] = f2bf(out);
    }
}

// ---------------- selective scan ----------------
// lane t: n = t&15, group g = t>>4 owns e = blockIdx.x*16 + g; b = blockIdx.y
// NOTE: delta and ys may ALIAS (read delta[l,e] strictly before masked write of
// ys[l,e] in the same wave iteration; e-ranges partitioned per block) -> no __restrict__.
__global__ __launch_bounds__(256) void scan_k(
    const ushort_t* __restrict__ xs, const ushort_t* delta,
    const ushort_t* __restrict__ bc, const ushort_t* __restrict__ skip,
    const float* __restrict__ A_log, const float* __restrict__ WD,
    ushort_t* ys)
{
    int t = threadIdx.x;
    int n = t & 15, g = t >> 4;
    int e = blockIdx.x * 16 + g;
    int b = blockIdx.y;
    float acoef = -expf(A_log[e * NN_ + n]) * 1.44269504f;  // A * log2(e)
    float wd = WD[e];
    size_t m0 = (size_t)b * LL_;
    const ushort_t* xp = xs    + m0 * EE_ + e;
    const ushort_t* dp = delta + m0 * EE_ + e;
    const ushort_t* bp = bc    + m0 * 160 + n;
    const ushort_t* cp = bp + 16;
    const ushort_t* sp = skip  + m0 * EE_ + e;
    ushort_t*       yp = ys    + m0 * EE_ + e;

    float h = 0.f;
    for (int l = 0; l < LL_; ++l) {
        float dlt = bf2f(dp[(size_t)l * EE_]);
        float xv  = bf2f(xp[(size_t)l * EE_]);
        float Bv  = bf2f(bp[(size_t)l * 160]);
        float Cv  = bf2f(cp[(size_t)l * 160]);
        float a = exp2f(dlt * acoef);
        h = fmaf(a, h, dlt * xv * Bv);
        float psum = h * Cv;
        psum += __shfl_xor(psum, 1);
        psum += __shfl_xor(psum, 2);
        psum += __shfl_xor(psum, 4);
        psum += __shfl_xor(psum, 8);
        if (n == 0) {
            float sk = bf2f(sp[(size_t)l * EE_]);
            float y = (psum + xv * wd) * (sk / (1.f + expf(-sk)));
            yp[(size_t)l * EE_] = f2bf(y);
        }
    }
}

// ---------------- launcher ----------------
// Workspace layout (112 MB total, lifetime-aliased):
//   A [16MB]: xn (rmsnorm -> gemm skip/in)      --> then Woutb (gemm out)
//   B [16MB]: Wskipb -> Winb -> {Wbcd1b 2MB | Wd2b 1MB | bcd1b 1.31MB}
//   C [32MB]: skipb (gemm skip -> scan)
//   D [32MB]: xin bf16 (gemm in -> conv) -> delta (gemm delta -> scan) -> ys (scan -> gemm out; ys aliases delta safely)
//   E [32MB]: xs (conv -> gemm bcd1, scan)
extern "C" void kernel_launch(void* const* d_in, const int* in_sizes, int n_in,
                              void* d_out, int out_size, void* d_ws, size_t ws_size,
                              hipStream_t stream) {
    const float* resid  = (const float*)d_in[0];
    const float* norm_w = (const float*)d_in[1];
    const float* W_skip = (const float*)d_in[2];
    const float* W_in   = (const float*)d_in[3];
    const float* conv_w = (const float*)d_in[4];
    const float* conv_b = (const float*)d_in[5];
    const float* W_d1   = (const float*)d_in[6];
    const float* W_d2   = (const float*)d_in[7];
    const float* b_d2   = (const float*)d_in[8];
    const float* W_Bm   = (const float*)d_in[9];
    const float* W_Cm   = (const float*)d_in[10];
    const float* A_log  = (const float*)d_in[11];
    const float* W_D    = (const float*)d_in[12];
    const float* W_out  = (const float*)d_in[13];
    float* out = (float*)d_out;

    const size_t MB16 = (size_t)16 * 1024 * 1024;
    const size_t MB32 = (size_t)32 * 1024 * 1024;
    char* w = (char*)d_ws;
    ushort_t* xn     = (ushort_t*)w;                  // region A
    ushort_t* woutb  = xn;                            // alias (after xn dead)
    w += MB16;
    ushort_t* wbuf   = (ushort_t*)w;                  // region B
    ushort_t* wbcd1b = wbuf;                          // [256][4096] = 2MB
    ushort_t* wd2b   = wbuf + (size_t)256 * EE_;      // [4096][128] = 1MB
    ushort_t* bcd1b  = wd2b + (size_t)EE_ * RR_;      // [4096][160] = 1.31MB
    w += MB16;
    ushort_t* skipb  = (ushort_t*)w; w += MB32;       // region C
    ushort_t* xinb   = (ushort_t*)w;                  // region D
    ushort_t* deltab = xinb;                          // alias (after xin dead)
    ushort_t* ysb    = xinb;                          // alias (read-before-write in scan)
    w += MB32;
    ushort_t* xsb    = (ushort_t*)w; w += MB32;       // region E

    // 1. RMSNorm -> xn (bf16)
    rmsnorm_k<<<MB_, 256, 0, stream>>>(resid, norm_w, xn);

    // 2. skip = xn @ W_skip^T  (bf16 out)
    cvt_bf16_k<<<8192, 256, 0, stream>>>(W_skip, wbuf, (EE_ * DD_) / 4);
    gemm_bt<<<dim3(EE_ / 128, MB_ / 128), 256, 0, stream>>>(
        xn, wbuf, DD_, DD_, DD_, skipb, EE_, EE_, nullptr, GMODE_BF16);

    // 3. xin = xn @ W_in^T  (bf16 out)
    cvt_bf16_k<<<8192, 256, 0, stream>>>(W_in, wbuf, (EE_ * DD_) / 4);
    gemm_bt<<<dim3(EE_ / 128, MB_ / 128), 256, 0, stream>>>(
        xn, wbuf, DD_, DD_, DD_, xinb, EE_, EE_, nullptr, GMODE_BF16);

    // 4. convert remaining weights (regions now free)
    cvt_bf16_k<<<8192, 256, 0, stream>>>(W_out, woutb, (DD_ * EE_) / 4);  // into region A
    pack_bcd1_k<<<1024, 256, 0, stream>>>(W_Bm, W_Cm, W_d1, wbcd1b);
    cvt_bf16_k<<<512, 256, 0, stream>>>(W_d2, wd2b, (EE_ * RR_) / 4);

    // 5. conv + silu -> xs (bf16)
    conv_silu_k<<<dim3(EE_ / 256, LL_ / 4, 2), 256, 0, stream>>>(xinb, conv_w, conv_b, xsb);

    // 6. [B|C|d1] = xs @ Wbcd1^T -> bcd1b (bf16, [4096,160])
    gemm_bt<<<dim3(2, MB_ / 128), 256, 0, stream>>>(
        xsb, wbcd1b, EE_, EE_, EE_, bcd1b, 160, 160, nullptr, GMODE_BF16);

    // 7. delta = softplus(d1 @ W_d2^T + b_d2) -> deltab (bf16, overwrites dead xin)
    gemm_bt<<<dim3(EE_ / 128, MB_ / 128), 256, 0, stream>>>(
        bcd1b + 32, wd2b, 160, RR_, RR_, deltab, EE_, EE_, b_d2, GMODE_SOFTPLUS);

    // 8. selective scan -> ys (bf16, aliases delta: read-before-write per element)
    scan_k<<<dim3(EE_ / 16, 2), 256, 0, stream>>>(
        xsb, deltab, bcd1b, skipb, A_log, W_D, ysb);

    // 9. out = resid + ys @ W_out^T (f32)
    gemm_bt<<<dim3(DD_ / 128, MB_ / 128), 256, 0, stream>>>(
        ysb, woutb, EE_, EE_, EE_, out, DD_, DD_, resid, GMODE_RESID);
}

// Round 3
// 979.121 us; speedup vs baseline: 2.3779x; 2.3779x over previous
//
#include <hip/hip_runtime.h>
#include <hip/hip_bf16.h>
#include <math.h>

// Problem constants
#define MB_ 4096   // B*L rows
#define DD_ 2048   // D
#define EE_ 4096   // E
#define LL_ 2048   // L
#define NN_ 16     // state dim
#define RR_ 128    // low-rank
#define CH_ 16     // scan chunks
#define LCH_ (LL_ / CH_)   // 128

using short8  = __attribute__((ext_vector_type(8))) short;
using floatx4 = __attribute__((ext_vector_type(4))) float;
typedef unsigned short ushort_t;

__device__ __forceinline__ float bf2f(ushort_t u) {
    unsigned int x = ((unsigned int)u) << 16;
    return __builtin_bit_cast(float, x);
}
__device__ __forceinline__ ushort_t f2bf(float f) {
    unsigned int x = __builtin_bit_cast(unsigned int, f);
    unsigned int lsb = (x >> 16) & 1u;
    x += 0x7fffu + lsb;
    return (ushort_t)(x >> 16);
}
__device__ __forceinline__ float bf_lo(unsigned int u) {
    return __builtin_bit_cast(float, u << 16);
}
__device__ __forceinline__ float bf_hi(unsigned int u) {
    return __builtin_bit_cast(float, u & 0xffff0000u);
}

// ---------------- weight conversion f32 -> bf16 ----------------
__global__ __launch_bounds__(256) void cvt_bf16_k(const float* __restrict__ src,
                                                  ushort_t* __restrict__ dst, int n4) {
    int i = blockIdx.x * 256 + threadIdx.x;
    if (i >= n4) return;
    float4 v = ((const float4*)src)[i];
    ushort_t* d = dst + (size_t)i * 4;
    d[0] = f2bf(v.x); d[1] = f2bf(v.y); d[2] = f2bf(v.z); d[3] = f2bf(v.w);
}

// pack W_Bm(16) + W_Cm(16) + W_d1(128) + zero-pad to [256][4096] bf16
__global__ __launch_bounds__(256) void pack_bcd1_k(const float* __restrict__ Wb,
                                                   const float* __restrict__ Wc,
                                                   const float* __restrict__ Wd1,
                                                   ushort_t* __restrict__ dst) {
    int i = blockIdx.x * 256 + threadIdx.x;      // i indexes groups of 4 elems
    int row = i >> 10;                            // (i*4)/4096
    int c4  = i & 1023;
    float4 v;
    if (row < 16)       v = ((const float4*)(Wb  + (size_t)row       * 4096))[c4];
    else if (row < 32)  v = ((const float4*)(Wc  + (size_t)(row - 16)* 4096))[c4];
    else if (row < 160) v = ((const float4*)(Wd1 + (size_t)(row - 32)* 4096))[c4];
    else { v.x = 0.f; v.y = 0.f; v.z = 0.f; v.w = 0.f; }
    ushort_t* d = dst + (size_t)i * 4;
    d[0] = f2bf(v.x); d[1] = f2bf(v.y); d[2] = f2bf(v.z); d[3] = f2bf(v.w);
}

// ---------------- RMSNorm ----------------
__global__ __launch_bounds__(256) void rmsnorm_k(const float* __restrict__ resid,
                                                 const float* __restrict__ nw,
                                                 ushort_t* __restrict__ xn) {
    __shared__ float red[4];
    int row = blockIdx.x;
    int tid = threadIdx.x;
    const float* rp = resid + (size_t)row * DD_;
    float4 a = ((const float4*)rp)[tid];
    float4 b = ((const float4*)rp)[tid + 256];
    float ss = a.x*a.x + a.y*a.y + a.z*a.z + a.w*a.w
             + b.x*b.x + b.y*b.y + b.z*b.z + b.w*b.w;
    #pragma unroll
    for (int off = 32; off; off >>= 1) ss += __shfl_xor(ss, off);
    int wave = tid >> 6;
    if ((tid & 63) == 0) red[wave] = ss;
    __syncthreads();
    float total = red[0] + red[1] + red[2] + red[3];
    float scale = rsqrtf(total * (1.0f / (float)DD_) + 1e-5f);
    ushort_t* op = xn + (size_t)row * DD_;
    int i0 = tid * 4;
    op[i0+0] = f2bf(a.x * scale * nw[i0+0]);
    op[i0+1] = f2bf(a.y * scale * nw[i0+1]);
    op[i0+2] = f2bf(a.z * scale * nw[i0+2]);
    op[i0+3] = f2bf(a.w * scale * nw[i0+3]);
    int i1 = (tid + 256) * 4;
    op[i1+0] = f2bf(b.x * scale * nw[i1+0]);
    op[i1+1] = f2bf(b.y * scale * nw[i1+1]);
    op[i1+2] = f2bf(b.z * scale * nw[i1+2]);
    op[i1+3] = f2bf(b.w * scale * nw[i1+3]);
}

// ---------------- bf16 MFMA GEMM: C[m,n] = sum_k A[m,k]*Bw[n,k] ----------------
#define GMODE_BF16     0
#define GMODE_F32      1
#define GMODE_SOFTPLUS 2
#define GMODE_RESID    3

__global__ __launch_bounds__(256) void gemm_bt(
    const ushort_t* __restrict__ A, const ushort_t* __restrict__ Bw,
    int lda, int ldb, int K,
    void* __restrict__ outp, int ldc, int ncols,
    const float* __restrict__ aux, int mode)
{
    __shared__ __align__(16) ushort_t As[128 * 32];
    __shared__ __align__(16) ushort_t Bs[128 * 32];
    const int tid  = threadIdx.x;
    const int lane = tid & 63;
    const int wave = tid >> 6;
    const int quad = lane >> 4;
    const int l16  = lane & 15;
    const int mb   = (wave & 1) * 64;
    const int nb   = (wave >> 1) * 64;
    const int tileM = blockIdx.y * 128;
    const int tileN = blockIdx.x * 128;

    const int r0   = tid >> 2;          // 0..63
    const int koff = (tid & 3) * 8;     // 0,8,16,24
    const ushort_t* Ag = A  + (size_t)(tileM + r0) * lda + koff;
    const ushort_t* Bg = Bw + (size_t)(tileN + r0) * ldb + koff;
    const int ldsoff = r0 * 32 + koff;

    floatx4 acc[4][4];
    #pragma unroll
    for (int i = 0; i < 4; i++)
        #pragma unroll
        for (int j = 0; j < 4; j++)
            acc[i][j] = (floatx4){0.f, 0.f, 0.f, 0.f};

    for (int kb = 0; kb < K; kb += 32) {
        uint4 a0 = *(const uint4*)(Ag + kb);
        uint4 a1 = *(const uint4*)(Ag + (size_t)64 * lda + kb);
        uint4 b0 = *(const uint4*)(Bg + kb);
        uint4 b1 = *(const uint4*)(Bg + (size_t)64 * ldb + kb);
        __syncthreads();
        *(uint4*)(As + ldsoff)           = a0;
        *(uint4*)(As + ldsoff + 64 * 32) = a1;
        *(uint4*)(Bs + ldsoff)           = b0;
        *(uint4*)(Bs + ldsoff + 64 * 32) = b1;
        __syncthreads();
        short8 af[4], bfr[4];
        #pragma unroll
        for (int i = 0; i < 4; i++)
            af[i] = *(const short8*)(As + (mb + i * 16 + l16) * 32 + quad * 8);
        #pragma unroll
        for (int j = 0; j < 4; j++)
            bfr[j] = *(const short8*)(Bs + (nb + j * 16 + l16) * 32 + quad * 8);
        #pragma unroll
        for (int i = 0; i < 4; i++)
            #pragma unroll
            for (int j = 0; j < 4; j++)
                acc[i][j] = __builtin_amdgcn_mfma_f32_16x16x32_bf16(af[i], bfr[j], acc[i][j], 0, 0, 0);
    }

    #pragma unroll
    for (int i = 0; i < 4; i++) {
        #pragma unroll
        for (int j = 0; j < 4; j++) {
            int col = tileN + nb + j * 16 + l16;
            if (col >= ncols) continue;
            int rowb = tileM + mb + i * 16 + quad * 4;
            #pragma unroll
            for (int r = 0; r < 4; r++) {
                size_t idx = (size_t)(rowb + r) * ldc + col;
                float v = acc[i][j][r];
                if (mode == GMODE_BF16) {
                    ((ushort_t*)outp)[idx] = f2bf(v);
                } else if (mode == GMODE_F32) {
                    ((float*)outp)[idx] = v;
                } else if (mode == GMODE_SOFTPLUS) {
                    float z = v + aux[col];
                    float sp = (z > 20.f) ? z : log1pf(expf(z));
                    ((ushort_t*)outp)[idx] = f2bf(sp);
                } else { // GMODE_RESID
                    ((float*)outp)[idx] = v + aux[idx];
                }
            }
        }
    }
}

// ---------------- depthwise causal conv (K=4) + bias + silu (bf16 in/out) ----------------
__global__ __launch_bounds__(256) void conv_silu_k(const ushort_t* __restrict__ xin,
                                                   const float* __restrict__ cw,
                                                   const float* __restrict__ cb,
                                                   ushort_t* __restrict__ xs) {
    int e  = blockIdx.x * 256 + threadIdx.x;
    int l0 = blockIdx.y * 4;
    int b  = blockIdx.z;
    float w0 = cw[e * 4 + 0], w1 = cw[e * 4 + 1], w2 = cw[e * 4 + 2], w3 = cw[e * 4 + 3];
    float bias = cb[e];
    const ushort_t* p = xin + ((size_t)(b * LL_ + l0)) * EE_ + e;
    ushort_t*       o = xs  + ((size_t)(b * LL_ + l0)) * EE_ + e;
    float v[7];
    #pragma unroll
    for (int j = 0; j < 7; j++) {
        int l = l0 + j - 3;
        v[j] = (l >= 0) ? bf2f(p[(ptrdiff_t)(j - 3) * EE_]) : 0.f;  // l0+3 <= L-1 always
    }
    #pragma unroll
    for (int r = 0; r < 4; r++) {
        float s = bias + v[r] * w0 + v[r+1] * w1 + v[r+2] * w2 + v[r+3] * w3;
        float out = s / (1.f + expf(-s));           // silu
        o[(size_t)r * EE_] = f2bf(out);
    }
}

// ---------------- chunked selective scan ----------------
// Pass 1: per (b,e,chunk): local scan h0=0 over LCH_ steps.
//   S[b][c][e][n] = local end state; P[b][c][e][n] = exp2(acoef[n]*sum(delta)).
// thread owns one e (256 consecutive e per block -> coalesced 2B loads).
__global__ __launch_bounds__(256) void scan1_k(
    const ushort_t* __restrict__ xs, const ushort_t* __restrict__ delta,
    const ushort_t* __restrict__ bc, const float* __restrict__ A_log,
    float* __restrict__ P, float* __restrict__ S)
{
    const int e = blockIdx.x * 256 + threadIdx.x;
    const int c = blockIdx.y;
    const int b = blockIdx.z;
    const int l0 = c * LCH_;

    float acoef[NN_];
    {
        const float4* ap = (const float4*)(A_log + (size_t)e * NN_);
        #pragma unroll
        for (int k = 0; k < 4; k++) {
            float4 v = ap[k];
            acoef[k*4+0] = -expf(v.x) * 1.44269504f;
            acoef[k*4+1] = -expf(v.y) * 1.44269504f;
            acoef[k*4+2] = -expf(v.z) * 1.44269504f;
            acoef[k*4+3] = -expf(v.w) * 1.44269504f;
        }
    }

    const size_t m0 = (size_t)(b * LL_ + l0);
    const ushort_t* dp  = delta + m0 * EE_ + e;
    const ushort_t* xp  = xs    + m0 * EE_ + e;
    const ushort_t* bcp = bc    + m0 * 160;

    float h[NN_];
    #pragma unroll
    for (int n = 0; n < NN_; n++) h[n] = 0.f;
    float sd = 0.f;

    for (int l = 0; l < LCH_; ++l) {
        float dlt = bf2f(*dp); dp += EE_;
        float xv  = bf2f(*xp); xp += EE_;
        unsigned int q[4];
        *(uint4*)q = *(const uint4*)(bcp);      // B[0:8]
        unsigned int q2[4];
        *(uint4*)q2 = *(const uint4*)(bcp + 8); // B[8:16]
        bcp += 160;
        sd += dlt;
        float dx = dlt * xv;
        float Bn[NN_];
        #pragma unroll
        for (int k = 0; k < 4; k++) {
            Bn[k*2+0] = bf_lo(q[k]);  Bn[k*2+1] = bf_hi(q[k]);
            Bn[8+k*2] = bf_lo(q2[k]); Bn[9+k*2] = bf_hi(q2[k]);
        }
        #pragma unroll
        for (int n = 0; n < NN_; n++) {
            float a = exp2f(dlt * acoef[n]);
            h[n] = fmaf(a, h[n], dx * Bn[n]);
        }
    }

    const size_t ob = (((size_t)(b * CH_ + c)) * EE_ + e) * NN_;
    float4* Pp = (float4*)(P + ob);
    float4* Sp = (float4*)(S + ob);
    #pragma unroll
    for (int k = 0; k < 4; k++) {
        float4 pv, sv;
        pv.x = exp2f(acoef[k*4+0] * sd); pv.y = exp2f(acoef[k*4+1] * sd);
        pv.z = exp2f(acoef[k*4+2] * sd); pv.w = exp2f(acoef[k*4+3] * sd);
        sv.x = h[k*4+0]; sv.y = h[k*4+1]; sv.z = h[k*4+2]; sv.w = h[k*4+3];
        Pp[k] = pv; Sp[k] = sv;
    }
}

// Pass 2: combine chunk carries sequentially; rewrite S[b][c][e][n] in place
// with the carry-IN state for chunk c.
__global__ __launch_bounds__(256) void scan2_k(const float* __restrict__ P, float* S) {
    int idx = blockIdx.x * 256 + threadIdx.x;   // (b, e*16+n)
    int b  = idx >> 16;
    int en = idx & 65535;
    size_t base = ((size_t)b * CH_) * (EE_ * NN_) + en;
    float h = 0.f;
    #pragma unroll
    for (int c = 0; c < CH_; c++) {
        size_t o = base + (size_t)c * (EE_ * NN_);
        float Pv = P[o];
        float Sv = S[o];
        S[o] = h;               // carry-in for chunk c
        h = fmaf(Pv, h, Sv);
    }
}

// Pass 3: redo local scans seeded with carries; emit y fused with D-term and
// silu(skip) gate. ys may alias delta (same-thread read-before-write per (l,e)).
__global__ __launch_bounds__(256) void scan3_k(
    const ushort_t* __restrict__ xs, const ushort_t* delta,
    const ushort_t* __restrict__ bc, const ushort_t* __restrict__ skip,
    const float* __restrict__ A_log, const float* __restrict__ WD,
    const float* __restrict__ S, ushort_t* ys)
{
    const int e = blockIdx.x * 256 + threadIdx.x;
    const int c = blockIdx.y;
    const int b = blockIdx.z;
    const int l0 = c * LCH_;

    float acoef[NN_];
    {
        const float4* ap = (const float4*)(A_log + (size_t)e * NN_);
        #pragma unroll
        for (int k = 0; k < 4; k++) {
            float4 v = ap[k];
            acoef[k*4+0] = -expf(v.x) * 1.44269504f;
            acoef[k*4+1] = -expf(v.y) * 1.44269504f;
            acoef[k*4+2] = -expf(v.z) * 1.44269504f;
            acoef[k*4+3] = -expf(v.w) * 1.44269504f;
        }
    }
    const float wd = WD[e];

    float h[NN_];
    {
        const float4* Sp = (const float4*)(S + (((size_t)(b * CH_ + c)) * EE_ + e) * NN_);
        #pragma unroll
        for (int k = 0; k < 4; k++) {
            float4 v = Sp[k];
            h[k*4+0] = v.x; h[k*4+1] = v.y; h[k*4+2] = v.z; h[k*4+3] = v.w;
        }
    }

    const size_t m0 = (size_t)(b * LL_ + l0);
    const ushort_t* dp  = delta + m0 * EE_ + e;
    const ushort_t* xp  = xs    + m0 * EE_ + e;
    const ushort_t* sp  = skip  + m0 * EE_ + e;
    const ushort_t* bcp = bc    + m0 * 160;
    ushort_t*       yp  = ys    + m0 * EE_ + e;

    for (int l = 0; l < LCH_; ++l) {
        float dlt = bf2f(*dp); dp += EE_;
        float xv  = bf2f(*xp); xp += EE_;
        float sk  = bf2f(*sp); sp += EE_;
        unsigned int q[8];
        *(uint4*)(q)     = *(const uint4*)(bcp);       // B[0:8]
        *(uint4*)(q + 4) = *(const uint4*)(bcp + 8);   // B[8:16]
        unsigned int r[8];
        *(uint4*)(r)     = *(const uint4*)(bcp + 16);  // C[0:8]
        *(uint4*)(r + 4) = *(const uint4*)(bcp + 24);  // C[8:16]
        bcp += 160;
        float dx = dlt * xv;
        float y = 0.f;
        #pragma unroll
        for (int k = 0; k < 8; k++) {
            float B0 = bf_lo(q[k]), B1 = bf_hi(q[k]);
            float C0 = bf_lo(r[k]), C1 = bf_hi(r[k]);
            float a0 = exp2f(dlt * acoef[k*2+0]);
            float a1 = exp2f(dlt * acoef[k*2+1]);
            h[k*2+0] = fmaf(a0, h[k*2+0], dx * B0);
            h[k*2+1] = fmaf(a1, h[k*2+1], dx * B1);
            y = fmaf(h[k*2+0], C0, y);
            y = fmaf(h[k*2+1], C1, y);
        }
        y = (y + xv * wd) * (sk / (1.f + expf(-sk)));
        *yp = f2bf(y); yp += EE_;
    }
}

// ---------------- launcher ----------------
// Workspace layout (112 MB total, lifetime-aliased):
//   A [16MB]: xn (rmsnorm -> gemm skip/in) -> P (scan1 -> scan2) -> Woutb (gemm out)
//   B [16MB]: Wskipb -> Winb -> [wbcd1b 2MB | wd2b 1MB | bcd1b 1.31MB | S 8.39MB]
//   C [32MB]: skipb (gemm skip -> scan3)
//   D [32MB]: xin bf16 (gemm in -> conv) -> delta (gemm delta -> scan) -> ys (scan3; aliases delta safely)
//   E [32MB]: xs (conv -> gemm bcd1, scan)
extern "C" void kernel_launch(void* const* d_in, const int* in_sizes, int n_in,
                              void* d_out, int out_size, void* d_ws, size_t ws_size,
                              hipStream_t stream) {
    const float* resid  = (const float*)d_in[0];
    const float* norm_w = (const float*)d_in[1];
    const float* W_skip = (const float*)d_in[2];
    const float* W_in   = (const float*)d_in[3];
    const float* conv_w = (const float*)d_in[4];
    const float* conv_b = (const float*)d_in[5];
    const float* W_d1   = (const float*)d_in[6];
    const float* W_d2   = (const float*)d_in[7];
    const float* b_d2   = (const float*)d_in[8];
    const float* W_Bm   = (const float*)d_in[9];
    const float* W_Cm   = (const float*)d_in[10];
    const float* A_log  = (const float*)d_in[11];
    const float* W_D    = (const float*)d_in[12];
    const float* W_out  = (const float*)d_in[13];
    float* out = (float*)d_out;

    const size_t MB16 = (size_t)16 * 1024 * 1024;
    const size_t MB32 = (size_t)32 * 1024 * 1024;
    char* w = (char*)d_ws;
    // region A
    ushort_t* xn     = (ushort_t*)w;
    float*    Pbuf   = (float*)w;                     // alias (after xn dead)
    ushort_t* woutb  = (ushort_t*)w;                  // alias (after P dead)
    w += MB16;
    // region B
    ushort_t* wbuf   = (ushort_t*)w;
    ushort_t* wbcd1b = wbuf;                          // [256][4096]  = 2 MB
    ushort_t* wd2b   = wbuf + (size_t)256 * EE_;      // [4096][128]  = 1 MB
    ushort_t* bcd1b  = wd2b + (size_t)EE_ * RR_;      // [4096][160]  = 1.31 MB
    float*    Sbuf   = (float*)(bcd1b + (size_t)MB_ * 160);  // 8.39 MB
    w += MB16;
    ushort_t* skipb  = (ushort_t*)w; w += MB32;       // region C
    ushort_t* xinb   = (ushort_t*)w;                  // region D
    ushort_t* deltab = xinb;                          // alias (after xin dead)
    ushort_t* ysb    = xinb;                          // alias (scan3 read-before-write)
    w += MB32;
    ushort_t* xsb    = (ushort_t*)w; w += MB32;       // region E

    // 1. RMSNorm -> xn (bf16)
    rmsnorm_k<<<MB_, 256, 0, stream>>>(resid, norm_w, xn);

    // 2. skip = xn @ W_skip^T  (bf16 out)
    cvt_bf16_k<<<8192, 256, 0, stream>>>(W_skip, wbuf, (EE_ * DD_) / 4);
    gemm_bt<<<dim3(EE_ / 128, MB_ / 128), 256, 0, stream>>>(
        xn, wbuf, DD_, DD_, DD_, skipb, EE_, EE_, nullptr, GMODE_BF16);

    // 3. xin = xn @ W_in^T  (bf16 out)
    cvt_bf16_k<<<8192, 256, 0, stream>>>(W_in, wbuf, (EE_ * DD_) / 4);
    gemm_bt<<<dim3(EE_ / 128, MB_ / 128), 256, 0, stream>>>(
        xn, wbuf, DD_, DD_, DD_, xinb, EE_, EE_, nullptr, GMODE_BF16);

    // 4. small weights into region B head (W_in bf16 now dead)
    pack_bcd1_k<<<1024, 256, 0, stream>>>(W_Bm, W_Cm, W_d1, wbcd1b);
    cvt_bf16_k<<<512, 256, 0, stream>>>(W_d2, wd2b, (EE_ * RR_) / 4);

    // 5. conv + silu -> xs (bf16)
    conv_silu_k<<<dim3(EE_ / 256, LL_ / 4, 2), 256, 0, stream>>>(xinb, conv_w, conv_b, xsb);

    // 6. [B|C|d1] = xs @ Wbcd1^T -> bcd1b (bf16, [4096,160])
    gemm_bt<<<dim3(2, MB_ / 128), 256, 0, stream>>>(
        xsb, wbcd1b, EE_, EE_, EE_, bcd1b, 160, 160, nullptr, GMODE_BF16);

    // 7. delta = softplus(d1 @ W_d2^T + b_d2) -> deltab (overwrites dead xin)
    gemm_bt<<<dim3(EE_ / 128, MB_ / 128), 256, 0, stream>>>(
        bcd1b + 32, wd2b, 160, RR_, RR_, deltab, EE_, EE_, b_d2, GMODE_SOFTPLUS);

    // 8. chunked selective scan
    scan1_k<<<dim3(EE_ / 256, CH_, 2), 256, 0, stream>>>(
        xsb, deltab, bcd1b, A_log, Pbuf, Sbuf);
    scan2_k<<<(2 * EE_ * NN_) / 256, 256, 0, stream>>>(Pbuf, Sbuf);
    scan3_k<<<dim3(EE_ / 256, CH_, 2), 256, 0, stream>>>(
        xsb, deltab, bcd1b, skipb, A_log, W_D, Sbuf, ysb);

    // 9. W_out -> bf16 into region A (P dead now), then out = resid + ys @ W_out^T
    cvt_bf16_k<<<8192, 256, 0, stream>>>(W_out, woutb, (DD_ * EE_) / 4);
    gemm_bt<<<dim3(DD_ / 128, MB_ / 128), 256, 0, stream>>>(
        ysb, woutb, EE_, EE_, EE_, out, DD_, DD_, resid, GMODE_RESID);
}

// Round 4
// 972.715 us; speedup vs baseline: 2.3936x; 1.0066x over previous
//
#include <hip/hip_runtime.h>
#include <hip/hip_bf16.h>
#include <math.h>

// Problem constants
#define MB_ 4096   // B*L rows
#define DD_ 2048   // D
#define EE_ 4096   // E
#define LL_ 2048   // L
#define NN_ 16     // state dim
#define RR_ 128    // low-rank
#define CH_ 16     // scan chunks
#define LCH_ (LL_ / CH_)   // 128

using short8  = __attribute__((ext_vector_type(8))) short;
using floatx4 = __attribute__((ext_vector_type(4))) float;
typedef unsigned short ushort_t;

__device__ __forceinline__ float bf2f(ushort_t u) {
    unsigned int x = ((unsigned int)u) << 16;
    return __builtin_bit_cast(float, x);
}
__device__ __forceinline__ ushort_t f2bf(float f) {
    unsigned int x = __builtin_bit_cast(unsigned int, f);
    unsigned int lsb = (x >> 16) & 1u;
    x += 0x7fffu + lsb;
    return (ushort_t)(x >> 16);
}
__device__ __forceinline__ float bf_lo(unsigned int u) {
    return __builtin_bit_cast(float, u << 16);
}
__device__ __forceinline__ float bf_hi(unsigned int u) {
    return __builtin_bit_cast(float, u & 0xffff0000u);
}

// async global->LDS, 16B per lane. LDS dest is wave-uniform base + lane*16.
__device__ __forceinline__ void gld16(const ushort_t* g, ushort_t* l) {
    __builtin_amdgcn_global_load_lds(
        (const __attribute__((address_space(1))) unsigned int*)g,
        (__attribute__((address_space(3))) unsigned int*)l,
        16, 0, 0);
}

// ---------------- weight conversion f32 -> bf16 ----------------
__global__ __launch_bounds__(256) void cvt_bf16_k(const float* __restrict__ src,
                                                  ushort_t* __restrict__ dst, int n4) {
    int i = blockIdx.x * 256 + threadIdx.x;
    if (i >= n4) return;
    float4 v = ((const float4*)src)[i];
    ushort_t* d = dst + (size_t)i * 4;
    d[0] = f2bf(v.x); d[1] = f2bf(v.y); d[2] = f2bf(v.z); d[3] = f2bf(v.w);
}

// pack W_Bm(16) + W_Cm(16) + W_d1(128) + zero-pad to [256][4096] bf16
__global__ __launch_bounds__(256) void pack_bcd1_k(const float* __restrict__ Wb,
                                                   const float* __restrict__ Wc,
                                                   const float* __restrict__ Wd1,
                                                   ushort_t* __restrict__ dst) {
    int i = blockIdx.x * 256 + threadIdx.x;      // i indexes groups of 4 elems
    int row = i >> 10;                            // (i*4)/4096
    int c4  = i & 1023;
    float4 v;
    if (row < 16)       v = ((const float4*)(Wb  + (size_t)row       * 4096))[c4];
    else if (row < 32)  v = ((const float4*)(Wc  + (size_t)(row - 16)* 4096))[c4];
    else if (row < 160) v = ((const float4*)(Wd1 + (size_t)(row - 32)* 4096))[c4];
    else { v.x = 0.f; v.y = 0.f; v.z = 0.f; v.w = 0.f; }
    ushort_t* d = dst + (size_t)i * 4;
    d[0] = f2bf(v.x); d[1] = f2bf(v.y); d[2] = f2bf(v.z); d[3] = f2bf(v.w);
}

// ---------------- RMSNorm ----------------
__global__ __launch_bounds__(256) void rmsnorm_k(const float* __restrict__ resid,
                                                 const float* __restrict__ nw,
                                                 ushort_t* __restrict__ xn) {
    __shared__ float red[4];
    int row = blockIdx.x;
    int tid = threadIdx.x;
    const float* rp = resid + (size_t)row * DD_;
    float4 a = ((const float4*)rp)[tid];
    float4 b = ((const float4*)rp)[tid + 256];
    float ss = a.x*a.x + a.y*a.y + a.z*a.z + a.w*a.w
             + b.x*b.x + b.y*b.y + b.z*b.z + b.w*b.w;
    #pragma unroll
    for (int off = 32; off; off >>= 1) ss += __shfl_xor(ss, off);
    int wave = tid >> 6;
    if ((tid & 63) == 0) red[wave] = ss;
    __syncthreads();
    float total = red[0] + red[1] + red[2] + red[3];
    float scale = rsqrtf(total * (1.0f / (float)DD_) + 1e-5f);
    ushort_t* op = xn + (size_t)row * DD_;
    int i0 = tid * 4;
    op[i0+0] = f2bf(a.x * scale * nw[i0+0]);
    op[i0+1] = f2bf(a.y * scale * nw[i0+1]);
    op[i0+2] = f2bf(a.z * scale * nw[i0+2]);
    op[i0+3] = f2bf(a.w * scale * nw[i0+3]);
    int i1 = (tid + 256) * 4;
    op[i1+0] = f2bf(b.x * scale * nw[i1+0]);
    op[i1+1] = f2bf(b.y * scale * nw[i1+1]);
    op[i1+2] = f2bf(b.z * scale * nw[i1+2]);
    op[i1+3] = f2bf(b.w * scale * nw[i1+3]);
}

// ---------------- bf16 MFMA GEMM: C[m,n] = sum_k A[m,k]*Bw[n,k] ----------------
// m97-style: width-16 global_load_lds staging + k-chunk swizzle.
// LDS layout: row r (0..127) x 32 ushorts; row r's k-chunk q (8 bf16) stored at
// position p = (q + (r>>1)) & 3  -> quarter-wave ds_read_b128 phases are 2-way
// (free) instead of 8-way bank conflicts.
#define GMODE_BF16     0
#define GMODE_F32      1
#define GMODE_SOFTPLUS 2
#define GMODE_RESID    3

__global__ __launch_bounds__(256) void gemm_bt(
    const ushort_t* __restrict__ A, const ushort_t* __restrict__ Bw,
    int lda, int ldb, int K,
    void* __restrict__ outp, int ldc, int ncols,
    const float* __restrict__ aux, int mode)
{
    __shared__ __align__(16) ushort_t As[128 * 32];
    __shared__ __align__(16) ushort_t Bs[128 * 32];
    const int tid  = threadIdx.x;
    const int lane = tid & 63;
    const int wave = tid >> 6;
    const int quad = lane >> 4;
    const int l16  = lane & 15;
    const int mb   = (wave & 1) * 64;
    const int nb   = (wave >> 1) * 64;
    const int tileM = blockIdx.y * 128;
    const int tileN = blockIdx.x * 128;

    // staging addressing: thread covers row r0 (and r0+64), 16B chunk
    const int r0 = tid >> 2;                 // 0..63
    const int cpos = tid & 3;                // LDS position within row
    const int q    = (cpos - (r0 >> 1)) & 3; // global k-chunk fetched
    const int koff = q * 8;
    const ushort_t* Ag = A  + (size_t)(tileM + r0) * lda + koff;
    const ushort_t* Bg = Bw + (size_t)(tileN + r0) * ldb + koff;
    ushort_t* AsW0 = As + wave * 512;        // rows 16w..16w+15
    ushort_t* AsW1 = As + 2048 + wave * 512; // rows 64+16w..
    ushort_t* BsW0 = Bs + wave * 512;
    ushort_t* BsW1 = Bs + 2048 + wave * 512;

    floatx4 acc[4][4];
    #pragma unroll
    for (int i = 0; i < 4; i++)
        #pragma unroll
        for (int j = 0; j < 4; j++)
            acc[i][j] = (floatx4){0.f, 0.f, 0.f, 0.f};

    // fragment LDS addresses (swizzled): row R, chunk quad at pos (quad+(R>>1))&3
    int arow[4], apos[4];
    #pragma unroll
    for (int i = 0; i < 4; i++) {
        arow[i] = mb + i * 16 + l16;
        apos[i] = ((quad + (arow[i] >> 1)) & 3) * 8;
    }
    int brow[4], bpos[4];
    #pragma unroll
    for (int j = 0; j < 4; j++) {
        brow[j] = nb + j * 16 + l16;
        bpos[j] = ((quad + (brow[j] >> 1)) & 3) * 8;
    }

    for (int kb = 0; kb < K; kb += 32) {
        __syncthreads();                     // all waves done reading LDS
        gld16(Ag + kb, AsW0);
        gld16(Ag + (size_t)64 * lda + kb, AsW1);
        gld16(Bg + kb, BsW0);
        gld16(Bg + (size_t)64 * ldb + kb, BsW1);
        __syncthreads();                     // vmcnt(0) drain -> LDS ready
        short8 af[4], bfr[4];
        #pragma unroll
        for (int i = 0; i < 4; i++)
            af[i] = *(const short8*)(As + arow[i] * 32 + apos[i]);
        #pragma unroll
        for (int j = 0; j < 4; j++)
            bfr[j] = *(const short8*)(Bs + brow[j] * 32 + bpos[j]);
        #pragma unroll
        for (int i = 0; i < 4; i++)
            #pragma unroll
            for (int j = 0; j < 4; j++)
                acc[i][j] = __builtin_amdgcn_mfma_f32_16x16x32_bf16(af[i], bfr[j], acc[i][j], 0, 0, 0);
    }

    #pragma unroll
    for (int i = 0; i < 4; i++) {
        #pragma unroll
        for (int j = 0; j < 4; j++) {
            int col = tileN + nb + j * 16 + l16;
            if (col >= ncols) continue;
            int rowb = tileM + mb + i * 16 + quad * 4;
            #pragma unroll
            for (int r = 0; r < 4; r++) {
                size_t idx = (size_t)(rowb + r) * ldc + col;
                float v = acc[i][j][r];
                if (mode == GMODE_BF16) {
                    ((ushort_t*)outp)[idx] = f2bf(v);
                } else if (mode == GMODE_F32) {
                    ((float*)outp)[idx] = v;
                } else if (mode == GMODE_SOFTPLUS) {
                    float z = v + aux[col];
                    float sp = (z > 20.f) ? z : log1pf(expf(z));
                    ((ushort_t*)outp)[idx] = f2bf(sp);
                } else { // GMODE_RESID
                    ((float*)outp)[idx] = v + aux[idx];
                }
            }
        }
    }
}

// ---------------- depthwise causal conv (K=4) + bias + silu (bf16 in/out) ----------------
__global__ __launch_bounds__(256) void conv_silu_k(const ushort_t* __restrict__ xin,
                                                   const float* __restrict__ cw,
                                                   const float* __restrict__ cb,
                                                   ushort_t* __restrict__ xs) {
    int e  = blockIdx.x * 256 + threadIdx.x;
    int l0 = blockIdx.y * 4;
    int b  = blockIdx.z;
    float w0 = cw[e * 4 + 0], w1 = cw[e * 4 + 1], w2 = cw[e * 4 + 2], w3 = cw[e * 4 + 3];
    float bias = cb[e];
    const ushort_t* p = xin + ((size_t)(b * LL_ + l0)) * EE_ + e;
    ushort_t*       o = xs  + ((size_t)(b * LL_ + l0)) * EE_ + e;
    float v[7];
    #pragma unroll
    for (int j = 0; j < 7; j++) {
        int l = l0 + j - 3;
        v[j] = (l >= 0) ? bf2f(p[(ptrdiff_t)(j - 3) * EE_]) : 0.f;  // l0+3 <= L-1 always
    }
    #pragma unroll
    for (int r = 0; r < 4; r++) {
        float s = bias + v[r] * w0 + v[r+1] * w1 + v[r+2] * w2 + v[r+3] * w3;
        float out = s / (1.f + expf(-s));           // silu
        o[(size_t)r * EE_] = f2bf(out);
    }
}

// ---------------- chunked selective scan ----------------
__global__ __launch_bounds__(256) void scan1_k(
    const ushort_t* __restrict__ xs, const ushort_t* __restrict__ delta,
    const ushort_t* __restrict__ bc, const float* __restrict__ A_log,
    float* __restrict__ P, float* __restrict__ S)
{
    const int e = blockIdx.x * 256 + threadIdx.x;
    const int c = blockIdx.y;
    const int b = blockIdx.z;
    const int l0 = c * LCH_;

    float acoef[NN_];
    {
        const float4* ap = (const float4*)(A_log + (size_t)e * NN_);
        #pragma unroll
        for (int k = 0; k < 4; k++) {
            float4 v = ap[k];
            acoef[k*4+0] = -expf(v.x) * 1.44269504f;
            acoef[k*4+1] = -expf(v.y) * 1.44269504f;
            acoef[k*4+2] = -expf(v.z) * 1.44269504f;
            acoef[k*4+3] = -expf(v.w) * 1.44269504f;
        }
    }

    const size_t m0 = (size_t)(b * LL_ + l0);
    const ushort_t* dp  = delta + m0 * EE_ + e;
    const ushort_t* xp  = xs    + m0 * EE_ + e;
    const ushort_t* bcp = bc    + m0 * 160;

    float h[NN_];
    #pragma unroll
    for (int n = 0; n < NN_; n++) h[n] = 0.f;
    float sd = 0.f;

    for (int l = 0; l < LCH_; ++l) {
        float dlt = bf2f(*dp); dp += EE_;
        float xv  = bf2f(*xp); xp += EE_;
        unsigned int q[4];
        *(uint4*)q = *(const uint4*)(bcp);      // B[0:8]
        unsigned int q2[4];
        *(uint4*)q2 = *(const uint4*)(bcp + 8); // B[8:16]
        bcp += 160;
        sd += dlt;
        float dx = dlt * xv;
        float Bn[NN_];
        #pragma unroll
        for (int k = 0; k < 4; k++) {
            Bn[k*2+0] = bf_lo(q[k]);  Bn[k*2+1] = bf_hi(q[k]);
            Bn[8+k*2] = bf_lo(q2[k]); Bn[9+k*2] = bf_hi(q2[k]);
        }
        #pragma unroll
        for (int n = 0; n < NN_; n++) {
            float a = exp2f(dlt * acoef[n]);
            h[n] = fmaf(a, h[n], dx * Bn[n]);
        }
    }

    const size_t ob = (((size_t)(b * CH_ + c)) * EE_ + e) * NN_;
    float4* Pp = (float4*)(P + ob);
    float4* Sp = (float4*)(S + ob);
    #pragma unroll
    for (int k = 0; k < 4; k++) {
        float4 pv, sv;
        pv.x = exp2f(acoef[k*4+0] * sd); pv.y = exp2f(acoef[k*4+1] * sd);
        pv.z = exp2f(acoef[k*4+2] * sd); pv.w = exp2f(acoef[k*4+3] * sd);
        sv.x = h[k*4+0]; sv.y = h[k*4+1]; sv.z = h[k*4+2]; sv.w = h[k*4+3];
        Pp[k] = pv; Sp[k] = sv;
    }
}

// Pass 2: combine chunk carries sequentially; rewrite S in place with carry-in.
__global__ __launch_bounds__(256) void scan2_k(const float* __restrict__ P, float* S) {
    int idx = blockIdx.x * 256 + threadIdx.x;   // (b, e*16+n)
    int b  = idx >> 16;
    int en = idx & 65535;
    size_t base = ((size_t)b * CH_) * (EE_ * NN_) + en;
    float h = 0.f;
    #pragma unroll
    for (int c = 0; c < CH_; c++) {
        size_t o = base + (size_t)c * (EE_ * NN_);
        float Pv = P[o];
        float Sv = S[o];
        S[o] = h;               // carry-in for chunk c
        h = fmaf(Pv, h, Sv);
    }
}

// Pass 3: redo local scans seeded with carries; emit y fused with D-term and
// silu(skip) gate. ys may alias delta (same-thread read-before-write per (l,e)).
__global__ __launch_bounds__(256) void scan3_k(
    const ushort_t* __restrict__ xs, const ushort_t* delta,
    const ushort_t* __restrict__ bc, const ushort_t* __restrict__ skip,
    const float* __restrict__ A_log, const float* __restrict__ WD,
    const float* __restrict__ S, ushort_t* ys)
{
    const int e = blockIdx.x * 256 + threadIdx.x;
    const int c = blockIdx.y;
    const int b = blockIdx.z;
    const int l0 = c * LCH_;

    float acoef[NN_];
    {
        const float4* ap = (const float4*)(A_log + (size_t)e * NN_);
        #pragma unroll
        for (int k = 0; k < 4; k++) {
            float4 v = ap[k];
            acoef[k*4+0] = -expf(v.x) * 1.44269504f;
            acoef[k*4+1] = -expf(v.y) * 1.44269504f;
            acoef[k*4+2] = -expf(v.z) * 1.44269504f;
            acoef[k*4+3] = -expf(v.w) * 1.44269504f;
        }
    }
    const float wd = WD[e];

    float h[NN_];
    {
        const float4* Sp = (const float4*)(S + (((size_t)(b * CH_ + c)) * EE_ + e) * NN_);
        #pragma unroll
        for (int k = 0; k < 4; k++) {
            float4 v = Sp[k];
            h[k*4+0] = v.x; h[k*4+1] = v.y; h[k*4+2] = v.z; h[k*4+3] = v.w;
        }
    }

    const size_t m0 = (size_t)(b * LL_ + l0);
    const ushort_t* dp  = delta + m0 * EE_ + e;
    const ushort_t* xp  = xs    + m0 * EE_ + e;
    const ushort_t* sp  = skip  + m0 * EE_ + e;
    const ushort_t* bcp = bc    + m0 * 160;
    ushort_t*       yp  = ys    + m0 * EE_ + e;

    for (int l = 0; l < LCH_; ++l) {
        float dlt = bf2f(*dp); dp += EE_;
        float xv  = bf2f(*xp); xp += EE_;
        float sk  = bf2f(*sp); sp += EE_;
        unsigned int q[8];
        *(uint4*)(q)     = *(const uint4*)(bcp);       // B[0:8]
        *(uint4*)(q + 4) = *(const uint4*)(bcp + 8);   // B[8:16]
        unsigned int r[8];
        *(uint4*)(r)     = *(const uint4*)(bcp + 16);  // C[0:8]
        *(uint4*)(r + 4) = *(const uint4*)(bcp + 24);  // C[8:16]
        bcp += 160;
        float dx = dlt * xv;
        float y = 0.f;
        #pragma unroll
        for (int k = 0; k < 8; k++) {
            float B0 = bf_lo(q[k]), B1 = bf_hi(q[k]);
            float C0 = bf_lo(r[k]), C1 = bf_hi(r[k]);
            float a0 = exp2f(dlt * acoef[k*2+0]);
            float a1 = exp2f(dlt * acoef[k*2+1]);
            h[k*2+0] = fmaf(a0, h[k*2+0], dx * B0);
            h[k*2+1] = fmaf(a1, h[k*2+1], dx * B1);
            y = fmaf(h[k*2+0], C0, y);
            y = fmaf(h[k*2+1], C1, y);
        }
        y = (y + xv * wd) * (sk / (1.f + expf(-sk)));
        *yp = f2bf(y); yp += EE_;
    }
}

// ---------------- launcher ----------------
// Workspace layout (112 MB total, lifetime-aliased):
//   A [16MB]: xn (rmsnorm -> gemm skip/in) -> P (scan1 -> scan2) -> Woutb (gemm out)
//   B [16MB]: Wskipb -> Winb -> [wbcd1b 2MB | wd2b 1MB | bcd1b 1.31MB | S 8.39MB]
//   C [32MB]: skipb (gemm skip -> scan3)
//   D [32MB]: xin bf16 (gemm in -> conv) -> delta (gemm delta -> scan) -> ys (scan3; aliases delta safely)
//   E [32MB]: xs (conv -> gemm bcd1, scan)
extern "C" void kernel_launch(void* const* d_in, const int* in_sizes, int n_in,
                              void* d_out, int out_size, void* d_ws, size_t ws_size,
                              hipStream_t stream) {
    const float* resid  = (const float*)d_in[0];
    const float* norm_w = (const float*)d_in[1];
    const float* W_skip = (const float*)d_in[2];
    const float* W_in   = (const float*)d_in[3];
    const float* conv_w = (const float*)d_in[4];
    const float* conv_b = (const float*)d_in[5];
    const float* W_d1   = (const float*)d_in[6];
    const float* W_d2   = (const float*)d_in[7];
    const float* b_d2   = (const float*)d_in[8];
    const float* W_Bm   = (const float*)d_in[9];
    const float* W_Cm   = (const float*)d_in[10];
    const float* A_log  = (const float*)d_in[11];
    const float* W_D    = (const float*)d_in[12];
    const float* W_out  = (const float*)d_in[13];
    float* out = (float*)d_out;

    const size_t MB16 = (size_t)16 * 1024 * 1024;
    const size_t MB32 = (size_t)32 * 1024 * 1024;
    char* w = (char*)d_ws;
    // region A
    ushort_t* xn     = (ushort_t*)w;
    float*    Pbuf   = (float*)w;                     // alias (after xn dead)
    ushort_t* woutb  = (ushort_t*)w;                  // alias (after P dead)
    w += MB16;
    // region B
    ushort_t* wbuf   = (ushort_t*)w;
    ushort_t* wbcd1b = wbuf;                          // [256][4096]  = 2 MB
    ushort_t* wd2b   = wbuf + (size_t)256 * EE_;      // [4096][128]  = 1 MB
    ushort_t* bcd1b  = wd2b + (size_t)EE_ * RR_;      // [4096][160]  = 1.31 MB
    float*    Sbuf   = (float*)(bcd1b + (size_t)MB_ * 160);  // 8.39 MB
    w += MB16;
    ushort_t* skipb  = (ushort_t*)w; w += MB32;       // region C
    ushort_t* xinb   = (ushort_t*)w;                  // region D
    ushort_t* deltab = xinb;                          // alias (after xin dead)
    ushort_t* ysb    = xinb;                          // alias (scan3 read-before-write)
    w += MB32;
    ushort_t* xsb    = (ushort_t*)w; w += MB32;       // region E

    // 1. RMSNorm -> xn (bf16)
    rmsnorm_k<<<MB_, 256, 0, stream>>>(resid, norm_w, xn);

    // 2. skip = xn @ W_skip^T  (bf16 out)
    cvt_bf16_k<<<8192, 256, 0, stream>>>(W_skip, wbuf, (EE_ * DD_) / 4);
    gemm_bt<<<dim3(EE_ / 128, MB_ / 128), 256, 0, stream>>>(
        xn, wbuf, DD_, DD_, DD_, skipb, EE_, EE_, nullptr, GMODE_BF16);

    // 3. xin = xn @ W_in^T  (bf16 out)
    cvt_bf16_k<<<8192, 256, 0, stream>>>(W_in, wbuf, (EE_ * DD_) / 4);
    gemm_bt<<<dim3(EE_ / 128, MB_ / 128), 256, 0, stream>>>(
        xn, wbuf, DD_, DD_, DD_, xinb, EE_, EE_, nullptr, GMODE_BF16);

    // 4. small weights into region B head (W_in bf16 now dead)
    pack_bcd1_k<<<1024, 256, 0, stream>>>(W_Bm, W_Cm, W_d1, wbcd1b);
    cvt_bf16_k<<<512, 256, 0, stream>>>(W_d2, wd2b, (EE_ * RR_) / 4);

    // 5. conv + silu -> xs (bf16)
    conv_silu_k<<<dim3(EE_ / 256, LL_ / 4, 2), 256, 0, stream>>>(xinb, conv_w, conv_b, xsb);

    // 6. [B|C|d1] = xs @ Wbcd1^T -> bcd1b (bf16, [4096,160])
    gemm_bt<<<dim3(2, MB_ / 128), 256, 0, stream>>>(
        xsb, wbcd1b, EE_, EE_, EE_, bcd1b, 160, 160, nullptr, GMODE_BF16);

    // 7. delta = softplus(d1 @ W_d2^T + b_d2) -> deltab (overwrites dead xin)
    gemm_bt<<<dim3(EE_ / 128, MB_ / 128), 256, 0, stream>>>(
        bcd1b + 32, wd2b, 160, RR_, RR_, deltab, EE_, EE_, b_d2, GMODE_SOFTPLUS);

    // 8. chunked selective scan
    scan1_k<<<dim3(EE_ / 256, CH_, 2), 256, 0, stream>>>(
        xsb, deltab, bcd1b, A_log, Pbuf, Sbuf);
    scan2_k<<<(2 * EE_ * NN_) / 256, 256, 0, stream>>>(Pbuf, Sbuf);
    scan3_k<<<dim3(EE_ / 256, CH_, 2), 256, 0, stream>>>(
        xsb, deltab, bcd1b, skipb, A_log, W_D, Sbuf, ysb);

    // 9. W_out -> bf16 into region A (P dead now), then out = resid + ys @ W_out^T
    cvt_bf16_k<<<8192, 256, 0, stream>>>(W_out, woutb, (DD_ * EE_) / 4);
    gemm_bt<<<dim3(DD_ / 128, MB_ / 128), 256, 0, stream>>>(
        ysb, woutb, EE_, EE_, EE_, out, DD_, DD_, resid, GMODE_RESID);
}

// Round 5
// 909.978 us; speedup vs baseline: 2.5586x; 1.0689x over previous
//
#include <hip/hip_runtime.h>
#include <hip/hip_bf16.h>
#include <math.h>

// Problem constants
#define MB_ 4096   // B*L rows
#define DD_ 2048   // D
#define EE_ 4096   // E
#define LL_ 2048   // L
#define NN_ 16     // state dim
#define RR_ 128    // low-rank
#define CH_ 16     // scan chunks
#define LCH_ (LL_ / CH_)   // 128

using short8  = __attribute__((ext_vector_type(8))) short;
using floatx4 = __attribute__((ext_vector_type(4))) float;
typedef unsigned short ushort_t;

__device__ __forceinline__ float bf2f(ushort_t u) {
    unsigned int x = ((unsigned int)u) << 16;
    return __builtin_bit_cast(float, x);
}
__device__ __forceinline__ ushort_t f2bf(float f) {
    unsigned int x = __builtin_bit_cast(unsigned int, f);
    unsigned int lsb = (x >> 16) & 1u;
    x += 0x7fffu + lsb;
    return (ushort_t)(x >> 16);
}
__device__ __forceinline__ float bf_lo(unsigned int u) {
    return __builtin_bit_cast(float, u << 16);
}
__device__ __forceinline__ float bf_hi(unsigned int u) {
    return __builtin_bit_cast(float, u & 0xffff0000u);
}

// async global->LDS, 16B per lane. LDS dest is wave-uniform base + lane*16.
__device__ __forceinline__ void gld16(const ushort_t* g, ushort_t* l) {
    __builtin_amdgcn_global_load_lds(
        (const __attribute__((address_space(1))) unsigned int*)g,
        (__attribute__((address_space(3))) unsigned int*)l,
        16, 0, 0);
}

// ---------------- weight conversion f32 -> bf16 ----------------
__global__ __launch_bounds__(256) void cvt_bf16_k(const float* __restrict__ src,
                                                  ushort_t* __restrict__ dst, int n4) {
    int i = blockIdx.x * 256 + threadIdx.x;
    if (i >= n4) return;
    float4 v = ((const float4*)src)[i];
    ushort_t* d = dst + (size_t)i * 4;
    d[0] = f2bf(v.x); d[1] = f2bf(v.y); d[2] = f2bf(v.z); d[3] = f2bf(v.w);
}

// pack W_Bm(16) + W_Cm(16) + W_d1(128) + zero-pad to [256][4096] bf16
__global__ __launch_bounds__(256) void pack_bcd1_k(const float* __restrict__ Wb,
                                                   const float* __restrict__ Wc,
                                                   const float* __restrict__ Wd1,
                                                   ushort_t* __restrict__ dst) {
    int i = blockIdx.x * 256 + threadIdx.x;      // i indexes groups of 4 elems
    int row = i >> 10;                            // (i*4)/4096
    int c4  = i & 1023;
    float4 v;
    if (row < 16)       v = ((const float4*)(Wb  + (size_t)row       * 4096))[c4];
    else if (row < 32)  v = ((const float4*)(Wc  + (size_t)(row - 16)* 4096))[c4];
    else if (row < 160) v = ((const float4*)(Wd1 + (size_t)(row - 32)* 4096))[c4];
    else { v.x = 0.f; v.y = 0.f; v.z = 0.f; v.w = 0.f; }
    ushort_t* d = dst + (size_t)i * 4;
    d[0] = f2bf(v.x); d[1] = f2bf(v.y); d[2] = f2bf(v.z); d[3] = f2bf(v.w);
}

// ---------------- RMSNorm ----------------
__global__ __launch_bounds__(256) void rmsnorm_k(const float* __restrict__ resid,
                                                 const float* __restrict__ nw,
                                                 ushort_t* __restrict__ xn) {
    __shared__ float red[4];
    int row = blockIdx.x;
    int tid = threadIdx.x;
    const float* rp = resid + (size_t)row * DD_;
    float4 a = ((const float4*)rp)[tid];
    float4 b = ((const float4*)rp)[tid + 256];
    float ss = a.x*a.x + a.y*a.y + a.z*a.z + a.w*a.w
             + b.x*b.x + b.y*b.y + b.z*b.z + b.w*b.w;
    #pragma unroll
    for (int off = 32; off; off >>= 1) ss += __shfl_xor(ss, off);
    int wave = tid >> 6;
    if ((tid & 63) == 0) red[wave] = ss;
    __syncthreads();
    float total = red[0] + red[1] + red[2] + red[3];
    float scale = rsqrtf(total * (1.0f / (float)DD_) + 1e-5f);
    ushort_t* op = xn + (size_t)row * DD_;
    int i0 = tid * 4;
    op[i0+0] = f2bf(a.x * scale * nw[i0+0]);
    op[i0+1] = f2bf(a.y * scale * nw[i0+1]);
    op[i0+2] = f2bf(a.z * scale * nw[i0+2]);
    op[i0+3] = f2bf(a.w * scale * nw[i0+3]);
    int i1 = (tid + 256) * 4;
    op[i1+0] = f2bf(b.x * scale * nw[i1+0]);
    op[i1+1] = f2bf(b.y * scale * nw[i1+1]);
    op[i1+2] = f2bf(b.z * scale * nw[i1+2]);
    op[i1+3] = f2bf(b.w * scale * nw[i1+3]);
}

// ---------------- bf16 MFMA GEMM: C[m,n] = sum_k A[m,k]*Bw[n,k] ----------------
// BK=64 K-loop: 8 global_load_lds(16B) + 16 ds_read_b128 + 32 MFMA per barrier
// pair (amortizes the vmcnt(0) barrier drain over 2x MFMA vs BK=32).
// LDS tile: 128 rows x 8 slots of 16B (128B row = exact 32-bank period).
// Row r's k-chunk q lives at slot (q + (r>>1)) & 7 -> quarter-wave ds_read_b128
// phases hit 8 distinct 4-bank groups x 2 lanes = free 2-way.
#define GMODE_BF16     0
#define GMODE_F32      1
#define GMODE_SOFTPLUS 2
#define GMODE_RESID    3

__global__ __launch_bounds__(256) void gemm_bt(
    const ushort_t* __restrict__ A, const ushort_t* __restrict__ Bw,
    int lda, int ldb, int K,
    void* __restrict__ outp, int ldc, int ncols,
    const float* __restrict__ aux, int mode)
{
    __shared__ __align__(16) ushort_t As[128 * 64];
    __shared__ __align__(16) ushort_t Bs[128 * 64];
    const int tid  = threadIdx.x;
    const int lane = tid & 63;
    const int wave = tid >> 6;
    const int quad = lane >> 4;
    const int l16  = lane & 15;
    const int mb   = (wave & 1) * 64;
    const int nb   = (wave >> 1) * 64;
    const int tileM = blockIdx.y * 128;
    const int tileN = blockIdx.x * 128;

    // staging: instruction i of wave w covers rows [i*32 + w*8, +8);
    // lane l -> row + (l>>3), slot (l&7); fetches global chunk ((l&7)-(row>>1))&7
    const int srow = wave * 8 + (lane >> 3);          // row within 32-row group
    const int sq   = ((lane & 7) - (srow >> 1)) & 7;  // global k-chunk (same for all i)
    const ushort_t* Ag = A  + (size_t)(tileM + srow) * lda + sq * 8;
    const ushort_t* Bg = Bw + (size_t)(tileN + srow) * ldb + sq * 8;
    ushort_t* AsD = As + wave * 512;                  // +i*2048 per instruction
    ushort_t* BsD = Bs + wave * 512;

    floatx4 acc[4][4];
    #pragma unroll
    for (int i = 0; i < 4; i++)
        #pragma unroll
        for (int j = 0; j < 4; j++)
            acc[i][j] = (floatx4){0.f, 0.f, 0.f, 0.f};

    // fragment LDS offsets (ushort units), swizzled: row R, chunk kk*4+quad
    int aoff[4][2], boff[4][2];
    #pragma unroll
    for (int i = 0; i < 4; i++) {
        int ar = mb + i * 16 + l16;
        int br = nb + i * 16 + l16;
        #pragma unroll
        for (int kk = 0; kk < 2; kk++) {
            aoff[i][kk] = ar * 64 + (((kk * 4 + quad) + (ar >> 1)) & 7) * 8;
            boff[i][kk] = br * 64 + (((kk * 4 + quad) + (br >> 1)) & 7) * 8;
        }
    }

    for (int kb = 0; kb < K; kb += 64) {
        __syncthreads();                     // all waves done reading LDS
        #pragma unroll
        for (int i = 0; i < 4; i++) {
            gld16(Ag + (size_t)i * 32 * lda + kb, AsD + i * 2048);
            gld16(Bg + (size_t)i * 32 * ldb + kb, BsD + i * 2048);
        }
        __syncthreads();                     // vmcnt(0) drain -> LDS ready
        #pragma unroll
        for (int kk = 0; kk < 2; kk++) {
            short8 af[4], bfr[4];
            #pragma unroll
            for (int i = 0; i < 4; i++)
                af[i] = *(const short8*)(As + aoff[i][kk]);
            #pragma unroll
            for (int j = 0; j < 4; j++)
                bfr[j] = *(const short8*)(Bs + boff[j][kk]);
            #pragma unroll
            for (int i = 0; i < 4; i++)
                #pragma unroll
                for (int j = 0; j < 4; j++)
                    acc[i][j] = __builtin_amdgcn_mfma_f32_16x16x32_bf16(af[i], bfr[j], acc[i][j], 0, 0, 0);
        }
    }

    #pragma unroll
    for (int i = 0; i < 4; i++) {
        #pragma unroll
        for (int j = 0; j < 4; j++) {
            int col = tileN + nb + j * 16 + l16;
            if (col >= ncols) continue;
            int rowb = tileM + mb + i * 16 + quad * 4;
            #pragma unroll
            for (int r = 0; r < 4; r++) {
                size_t idx = (size_t)(rowb + r) * ldc + col;
                float v = acc[i][j][r];
                if (mode == GMODE_BF16) {
                    ((ushort_t*)outp)[idx] = f2bf(v);
                } else if (mode == GMODE_F32) {
                    ((float*)outp)[idx] = v;
                } else if (mode == GMODE_SOFTPLUS) {
                    float z = v + aux[col];
                    float sp = (z > 20.f) ? z : log1pf(expf(z));
                    ((ushort_t*)outp)[idx] = f2bf(sp);
                } else { // GMODE_RESID
                    ((float*)outp)[idx] = v + aux[idx];
                }
            }
        }
    }
}

// ---------------- depthwise causal conv (K=4) + bias + silu (bf16 in/out) ----------------
__global__ __launch_bounds__(256) void conv_silu_k(const ushort_t* __restrict__ xin,
                                                   const float* __restrict__ cw,
                                                   const float* __restrict__ cb,
                                                   ushort_t* __restrict__ xs) {
    int e  = blockIdx.x * 256 + threadIdx.x;
    int l0 = blockIdx.y * 4;
    int b  = blockIdx.z;
    float w0 = cw[e * 4 + 0], w1 = cw[e * 4 + 1], w2 = cw[e * 4 + 2], w3 = cw[e * 4 + 3];
    float bias = cb[e];
    const ushort_t* p = xin + ((size_t)(b * LL_ + l0)) * EE_ + e;
    ushort_t*       o = xs  + ((size_t)(b * LL_ + l0)) * EE_ + e;
    float v[7];
    #pragma unroll
    for (int j = 0; j < 7; j++) {
        int l = l0 + j - 3;
        v[j] = (l >= 0) ? bf2f(p[(ptrdiff_t)(j - 3) * EE_]) : 0.f;  // l0+3 <= L-1 always
    }
    #pragma unroll
    for (int r = 0; r < 4; r++) {
        float s = bias + v[r] * w0 + v[r+1] * w1 + v[r+2] * w2 + v[r+3] * w3;
        float out = s / (1.f + expf(-s));           // silu
        o[(size_t)r * EE_] = f2bf(out);
    }
}

// ---------------- chunked selective scan ----------------
__global__ __launch_bounds__(256) void scan1_k(
    const ushort_t* __restrict__ xs, const ushort_t* __restrict__ delta,
    const ushort_t* __restrict__ bc, const float* __restrict__ A_log,
    float* __restrict__ P, float* __restrict__ S)
{
    const int e = blockIdx.x * 256 + threadIdx.x;
    const int c = blockIdx.y;
    const int b = blockIdx.z;
    const int l0 = c * LCH_;

    float acoef[NN_];
    {
        const float4* ap = (const float4*)(A_log + (size_t)e * NN_);
        #pragma unroll
        for (int k = 0; k < 4; k++) {
            float4 v = ap[k];
            acoef[k*4+0] = -expf(v.x) * 1.44269504f;
            acoef[k*4+1] = -expf(v.y) * 1.44269504f;
            acoef[k*4+2] = -expf(v.z) * 1.44269504f;
            acoef[k*4+3] = -expf(v.w) * 1.44269504f;
        }
    }

    const size_t m0 = (size_t)(b * LL_ + l0);
    const ushort_t* dp  = delta + m0 * EE_ + e;
    const ushort_t* xp  = xs    + m0 * EE_ + e;
    const ushort_t* bcp = bc    + m0 * 160;

    float h[NN_];
    #pragma unroll
    for (int n = 0; n < NN_; n++) h[n] = 0.f;
    float sd = 0.f;

    for (int l = 0; l < LCH_; ++l) {
        float dlt = bf2f(*dp); dp += EE_;
        float xv  = bf2f(*xp); xp += EE_;
        unsigned int q[4];
        *(uint4*)q = *(const uint4*)(bcp);      // B[0:8]
        unsigned int q2[4];
        *(uint4*)q2 = *(const uint4*)(bcp + 8); // B[8:16]
        bcp += 160;
        sd += dlt;
        float dx = dlt * xv;
        float Bn[NN_];
        #pragma unroll
        for (int k = 0; k < 4; k++) {
            Bn[k*2+0] = bf_lo(q[k]);  Bn[k*2+1] = bf_hi(q[k]);
            Bn[8+k*2] = bf_lo(q2[k]); Bn[9+k*2] = bf_hi(q2[k]);
        }
        #pragma unroll
        for (int n = 0; n < NN_; n++) {
            float a = exp2f(dlt * acoef[n]);
            h[n] = fmaf(a, h[n], dx * Bn[n]);
        }
    }

    const size_t ob = (((size_t)(b * CH_ + c)) * EE_ + e) * NN_;
    float4* Pp = (float4*)(P + ob);
    float4* Sp = (float4*)(S + ob);
    #pragma unroll
    for (int k = 0; k < 4; k++) {
        float4 pv, sv;
        pv.x = exp2f(acoef[k*4+0] * sd); pv.y = exp2f(acoef[k*4+1] * sd);
        pv.z = exp2f(acoef[k*4+2] * sd); pv.w = exp2f(acoef[k*4+3] * sd);
        sv.x = h[k*4+0]; sv.y = h[k*4+1]; sv.z = h[k*4+2]; sv.w = h[k*4+3];
        Pp[k] = pv; Sp[k] = sv;
    }
}

// Pass 2: combine chunk carries sequentially; rewrite S in place with carry-in.
__global__ __launch_bounds__(256) void scan2_k(const float* __restrict__ P, float* S) {
    int idx = blockIdx.x * 256 + threadIdx.x;   // (b, e*16+n)
    int b  = idx >> 16;
    int en = idx & 65535;
    size_t base = ((size_t)b * CH_) * (EE_ * NN_) + en;
    float h = 0.f;
    #pragma unroll
    for (int c = 0; c < CH_; c++) {
        size_t o = base + (size_t)c * (EE_ * NN_);
        float Pv = P[o];
        float Sv = S[o];
        S[o] = h;               // carry-in for chunk c
        h = fmaf(Pv, h, Sv);
    }
}

// Pass 3: redo local scans seeded with carries; emit y fused with D-term and
// silu(skip) gate. ys may alias delta (same-thread read-before-write per (l,e)).
__global__ __launch_bounds__(256) void scan3_k(
    const ushort_t* __restrict__ xs, const ushort_t* delta,
    const ushort_t* __restrict__ bc, const ushort_t* __restrict__ skip,
    const float* __restrict__ A_log, const float* __restrict__ WD,
    const float* __restrict__ S, ushort_t* ys)
{
    const int e = blockIdx.x * 256 + threadIdx.x;
    const int c = blockIdx.y;
    const int b = blockIdx.z;
    const int l0 = c * LCH_;

    float acoef[NN_];
    {
        const float4* ap = (const float4*)(A_log + (size_t)e * NN_);
        #pragma unroll
        for (int k = 0; k < 4; k++) {
            float4 v = ap[k];
            acoef[k*4+0] = -expf(v.x) * 1.44269504f;
            acoef[k*4+1] = -expf(v.y) * 1.44269504f;
            acoef[k*4+2] = -expf(v.z) * 1.44269504f;
            acoef[k*4+3] = -expf(v.w) * 1.44269504f;
        }
    }
    const float wd = WD[e];

    float h[NN_];
    {
        const float4* Sp = (const float4*)(S + (((size_t)(b * CH_ + c)) * EE_ + e) * NN_);
        #pragma unroll
        for (int k = 0; k < 4; k++) {
            float4 v = Sp[k];
            h[k*4+0] = v.x; h[k*4+1] = v.y; h[k*4+2] = v.z; h[k*4+3] = v.w;
        }
    }

    const size_t m0 = (size_t)(b * LL_ + l0);
    const ushort_t* dp  = delta + m0 * EE_ + e;
    const ushort_t* xp  = xs    + m0 * EE_ + e;
    const ushort_t* sp  = skip  + m0 * EE_ + e;
    const ushort_t* bcp = bc    + m0 * 160;
    ushort_t*       yp  = ys    + m0 * EE_ + e;

    for (int l = 0; l < LCH_; ++l) {
        float dlt = bf2f(*dp); dp += EE_;
        float xv  = bf2f(*xp); xp += EE_;
        float sk  = bf2f(*sp); sp += EE_;
        unsigned int q[8];
        *(uint4*)(q)     = *(const uint4*)(bcp);       // B[0:8]
        *(uint4*)(q + 4) = *(const uint4*)(bcp + 8);   // B[8:16]
        unsigned int r[8];
        *(uint4*)(r)     = *(const uint4*)(bcp + 16);  // C[0:8]
        *(uint4*)(r + 4) = *(const uint4*)(bcp + 24);  // C[8:16]
        bcp += 160;
        float dx = dlt * xv;
        float y = 0.f;
        #pragma unroll
        for (int k = 0; k < 8; k++) {
            float B0 = bf_lo(q[k]), B1 = bf_hi(q[k]);
            float C0 = bf_lo(r[k]), C1 = bf_hi(r[k]);
            float a0 = exp2f(dlt * acoef[k*2+0]);
            float a1 = exp2f(dlt * acoef[k*2+1]);
            h[k*2+0] = fmaf(a0, h[k*2+0], dx * B0);
            h[k*2+1] = fmaf(a1, h[k*2+1], dx * B1);
            y = fmaf(h[k*2+0], C0, y);
            y = fmaf(h[k*2+1], C1, y);
        }
        y = (y + xv * wd) * (sk / (1.f + expf(-sk)));
        *yp = f2bf(y); yp += EE_;
    }
}

// ---------------- launcher ----------------
// Workspace layout (112 MB total, lifetime-aliased):
//   A [16MB]: xn (rmsnorm -> gemm skip/in) -> P (scan1 -> scan2) -> Woutb (gemm out)
//   B [16MB]: Wskipb -> Winb -> [wbcd1b 2MB | wd2b 1MB | bcd1b 1.31MB | S 8.39MB]
//   C [32MB]: skipb (gemm skip -> scan3)
//   D [32MB]: xin bf16 (gemm in -> conv) -> delta (gemm delta -> scan) -> ys (scan3; aliases delta safely)
//   E [32MB]: xs (conv -> gemm bcd1, scan)
extern "C" void kernel_launch(void* const* d_in, const int* in_sizes, int n_in,
                              void* d_out, int out_size, void* d_ws, size_t ws_size,
                              hipStream_t stream) {
    const float* resid  = (const float*)d_in[0];
    const float* norm_w = (const float*)d_in[1];
    const float* W_skip = (const float*)d_in[2];
    const float* W_in   = (const float*)d_in[3];
    const float* conv_w = (const float*)d_in[4];
    const float* conv_b = (const float*)d_in[5];
    const float* W_d1   = (const float*)d_in[6];
    const float* W_d2   = (const float*)d_in[7];
    const float* b_d2   = (const float*)d_in[8];
    const float* W_Bm   = (const float*)d_in[9];
    const float* W_Cm   = (const float*)d_in[10];
    const float* A_log  = (const float*)d_in[11];
    const float* W_D    = (const float*)d_in[12];
    const float* W_out  = (const float*)d_in[13];
    float* out = (float*)d_out;

    const size_t MB16 = (size_t)16 * 1024 * 1024;
    const size_t MB32 = (size_t)32 * 1024 * 1024;
    char* w = (char*)d_ws;
    // region A
    ushort_t* xn     = (ushort_t*)w;
    float*    Pbuf   = (float*)w;                     // alias (after xn dead)
    ushort_t* woutb  = (ushort_t*)w;                  // alias (after P dead)
    w += MB16;
    // region B
    ushort_t* wbuf   = (ushort_t*)w;
    ushort_t* wbcd1b = wbuf;                          // [256][4096]  = 2 MB
    ushort_t* wd2b   = wbuf + (size_t)256 * EE_;      // [4096][128]  = 1 MB
    ushort_t* bcd1b  = wd2b + (size_t)EE_ * RR_;      // [4096][160]  = 1.31 MB
    float*    Sbuf   = (float*)(bcd1b + (size_t)MB_ * 160);  // 8.39 MB
    w += MB16;
    ushort_t* skipb  = (ushort_t*)w; w += MB32;       // region C
    ushort_t* xinb   = (ushort_t*)w;                  // region D
    ushort_t* deltab = xinb;                          // alias (after xin dead)
    ushort_t* ysb    = xinb;                          // alias (scan3 read-before-write)
    w += MB32;
    ushort_t* xsb    = (ushort_t*)w; w += MB32;       // region E

    // 1. RMSNorm -> xn (bf16)
    rmsnorm_k<<<MB_, 256, 0, stream>>>(resid, norm_w, xn);

    // 2. skip = xn @ W_skip^T  (bf16 out)
    cvt_bf16_k<<<8192, 256, 0, stream>>>(W_skip, wbuf, (EE_ * DD_) / 4);
    gemm_bt<<<dim3(EE_ / 128, MB_ / 128), 256, 0, stream>>>(
        xn, wbuf, DD_, DD_, DD_, skipb, EE_, EE_, nullptr, GMODE_BF16);

    // 3. xin = xn @ W_in^T  (bf16 out)
    cvt_bf16_k<<<8192, 256, 0, stream>>>(W_in, wbuf, (EE_ * DD_) / 4);
    gemm_bt<<<dim3(EE_ / 128, MB_ / 128), 256, 0, stream>>>(
        xn, wbuf, DD_, DD_, DD_, xinb, EE_, EE_, nullptr, GMODE_BF16);

    // 4. small weights into region B head (W_in bf16 now dead)
    pack_bcd1_k<<<1024, 256, 0, stream>>>(W_Bm, W_Cm, W_d1, wbcd1b);
    cvt_bf16_k<<<512, 256, 0, stream>>>(W_d2, wd2b, (EE_ * RR_) / 4);

    // 5. conv + silu -> xs (bf16)
    conv_silu_k<<<dim3(EE_ / 256, LL_ / 4, 2), 256, 0, stream>>>(xinb, conv_w, conv_b, xsb);

    // 6. [B|C|d1] = xs @ Wbcd1^T -> bcd1b (bf16, [4096,160])
    gemm_bt<<<dim3(2, MB_ / 128), 256, 0, stream>>>(
        xsb, wbcd1b, EE_, EE_, EE_, bcd1b, 160, 160, nullptr, GMODE_BF16);

    // 7. delta = softplus(d1 @ W_d2^T + b_d2) -> deltab (overwrites dead xin)
    gemm_bt<<<dim3(EE_ / 128, MB_ / 128), 256, 0, stream>>>(
        bcd1b + 32, wd2b, 160, RR_, RR_, deltab, EE_, EE_, b_d2, GMODE_SOFTPLUS);

    // 8. chunked selective scan
    scan1_k<<<dim3(EE_ / 256, CH_, 2), 256, 0, stream>>>(
        xsb, deltab, bcd1b, A_log, Pbuf, Sbuf);
    scan2_k<<<(2 * EE_ * NN_) / 256, 256, 0, stream>>>(Pbuf, Sbuf);
    scan3_k<<<dim3(EE_ / 256, CH_, 2), 256, 0, stream>>>(
        xsb, deltab, bcd1b, skipb, A_log, W_D, Sbuf, ysb);

    // 9. W_out -> bf16 into region A (P dead now), then out = resid + ys @ W_out^T
    cvt_bf16_k<<<8192, 256, 0, stream>>>(W_out, woutb, (DD_ * EE_) / 4);
    gemm_bt<<<dim3(DD_ / 128, MB_ / 128), 256, 0, stream>>>(
        ysb, woutb, EE_, EE_, EE_, out, DD_, DD_, resid, GMODE_RESID);
}